// Round 13
// baseline (2721.561 us; speedup 1.0000x reference)
//
#include <hip/hip_runtime.h>
#include <math.h>

#define Bq 16
#define Tq 32
#define Wq 128
#define Rq 4
#define Nq 512
#define Mq 128
#define DINq 768
#define XIDq 919
#define BTWq (Bq*Tq*Wq)

// per-team payload arena (floats)
#define TSTRIDE 22272
#define TF_FW    0        // [8][4*512] fw partials
#define TF_BW    16384    // [4*512]
#define TF_RW    18432    // [4*512]
#define TF_WW    20480    // [512]
#define TF_PREC  20992    // [2][512] parity
#define TF_CNT   22016    // counters

struct P {
  const float *X, *hs0, *mem0;
  const int *rst;
  const float *Wb,*bb,*Wff1,*bff1,*Wff2,*bff2,*Wta,*bta,*Wtb,*btb,*Wv,*bv,*Wr,*br,*Wxi,*bxi;
  float *out;
  float *rdh,*teams;
  float *WbT,*Wff1T,*Wff2T,*WtaT,*WtbT,*WvT,*WrT,*WxiT;
};

__device__ __forceinline__ float dot4(float4 a, float4 b){
  return a.x*b.x + a.y*b.y + a.z*b.z + a.w*b.w;
}
__device__ __forceinline__ float sigf(float x){ return 1.f/(1.f+expf(-x)); }
__device__ __forceinline__ float oneplusf(float x){ return 1.f + log1pf(expf(x) + 1e-6f); }

__device__ __forceinline__ void pst(float* p, float v){
  __hip_atomic_store(p, v, __ATOMIC_RELAXED, __HIP_MEMORY_SCOPE_AGENT);
}
__device__ __forceinline__ float pld(float* p){
  return __hip_atomic_load(p, __ATOMIC_RELAXED, __HIP_MEMORY_SCOPE_AGENT);
}
__device__ __forceinline__ void bump(unsigned* f){
  __syncthreads();                      // drains all threads' payload stores
  if (threadIdx.x==0)
    __hip_atomic_fetch_add(f, 1u, __ATOMIC_RELAXED, __HIP_MEMORY_SCOPE_AGENT);
}
__device__ __forceinline__ void waitge(unsigned* f, unsigned v){
  if (threadIdx.x==0){
    while (__hip_atomic_load(f, __ATOMIC_RELAXED, __HIP_MEMORY_SCOPE_AGENT) < v)
      __builtin_amdgcn_s_sleep(1);
  }
  __syncthreads();
}

__device__ __forceinline__ float wave_sum64(float v){
  #pragma unroll
  for (int m=32;m>=1;m>>=1) v += __shfl_xor(v, m, 64);
  return v;
}
__device__ __forceinline__ float wave_max64(float v){
  #pragma unroll
  for (int m=32;m>=1;m>>=1) v = fmaxf(v, __shfl_xor(v, m, 64));
  return v;
}
__device__ __forceinline__ float blk_sum(float v, float* s8){
  int w = threadIdx.x>>6;
  v = wave_sum64(v);
  if ((threadIdx.x&63)==0) s8[w] = v;
  __syncthreads();
  float r = s8[0]+s8[1]+s8[2]+s8[3]+s8[4]+s8[5]+s8[6]+s8[7];
  __syncthreads();
  return r;
}
__device__ __forceinline__ float blk_max(float v, float* s8){
  int w = threadIdx.x>>6;
  v = wave_max64(v);
  if ((threadIdx.x&63)==0) s8[w] = v;
  __syncthreads();
  float r = s8[0];
  #pragma unroll
  for (int q=1;q<8;q++) r = fmaxf(r, s8[q]);
  __syncthreads();
  return r;
}
// reduce over rg bits (lane bits 3..5) within wave
__device__ __forceinline__ float red_rg(float v){
  v += __shfl_xor(v, 8, 64);
  v += __shfl_xor(v, 16, 64);
  v += __shfl_xor(v, 32, 64);
  return v;
}
// reduce over cg bits (lane bits 0..2)
__device__ __forceinline__ float red_cg(float v){
  v += __shfl_xor(v, 1, 8);
  v += __shfl_xor(v, 2, 8);
  v += __shfl_xor(v, 4, 8);
  return v;
}

// ---------- k_init: weight transposes + zero team arenas ----------
__global__ __launch_bounds__(256) void k_init(P p){
  int bid=blockIdx.x, tid=threadIdx.x;
  if (bid<8){ int idx=bid*256+tid, st=8*256;
    for (int k=idx;k<DINq*Wq;k+=st){ int j=k/DINq,i=k%DINq; p.WbT[k]=p.Wb[i*Wq+j]; }
  } else if (bid<10){ int idx=(bid-8)*256+tid, st=2*256;
    for (int k=idx;k<Wq*Wq;k+=st){ int j=k/Wq,i=k%Wq; p.Wff1T[k]=p.Wff1[i*Wq+j]; }
  } else if (bid<12){ int idx=(bid-10)*256+tid, st=2*256;
    for (int k=idx;k<Wq*Wq;k+=st){ int j=k/Wq,i=k%Wq; p.Wff2T[k]=p.Wff2[i*Wq+j]; }
  } else if (bid<14){ int idx=(bid-12)*256+tid, st=2*256;
    for (int k=idx;k<Wq*Wq;k+=st){ int j=k/Wq,i=k%Wq; p.WtaT[k]=p.Wta[i*Wq+j]; }
  } else if (bid<16){ int idx=(bid-14)*256+tid, st=2*256;
    for (int k=idx;k<Wq*Wq;k+=st){ int j=k/Wq,i=k%Wq; p.WtbT[k]=p.Wtb[i*Wq+j]; }
  } else if (bid<18){ int idx=(bid-16)*256+tid, st=2*256;
    for (int k=idx;k<Wq*Wq;k+=st){ int j=k/Wq,i=k%Wq; p.WvT[k]=p.Wv[i*Wq+j]; }
  } else if (bid<22){ int idx=(bid-18)*256+tid, st=4*256;
    for (int k=idx;k<Rq*Wq*Wq;k+=st){ int j=k/(Rq*Wq),i=k%(Rq*Wq); p.WrT[k]=p.Wr[i*Wq+j]; }
  } else if (bid<30){ int idx=(bid-22)*256+tid, st=8*256;
    for (int k=idx;k<XIDq*Wq;k+=st){ int f=k/Wq,i=k%Wq; p.WxiT[k]=p.Wxi[i*XIDq+f]; }
  } else if (bid<38){ int idx=(bid-30)*256+tid, st=8*256;
    for (int k=idx;k<16*TSTRIDE;k+=st) p.teams[k]=0.f;
  }
}

// ---------- k_run: 16 teams x (1 fat alpha + 8 link blocks) ----------
// Alpha holds ALL of its batch's memv in registers (m4[8][4], 128 VGPR) and
// does everything except the link update: combine, reads, z/hs/xi, wca, sort,
// ww/prec, mem update, rca. Links: 64-row register link update only.
// 2 cross-block hops per step: alpha->{rw,ww} ; links->{fw,bw}.
__global__ __launch_bounds__(512,1) void k_run(P p){
  const int tid=threadIdx.x, bid=blockIdx.x;
  const bool isA = (bid<16);
  const int team = isA ? bid : ((bid-16)>>3);
  const int g    = isA ? 0   : ((bid-16)&7);
  const int b=team;
  const int w=tid>>6, l=tid&63;
  const int rg=l>>3, cg=l&7, c0=cg*16;
  float* T = p.teams + (size_t)team*TSTRIDE;
  unsigned* C = (unsigned*)(T+TF_CNT);
  unsigned* CNT_FW=C+0; unsigned* FLAG_RW=C+32; unsigned* FLAG_WW=C+64;

  __shared__ __align__(16) float rwl[Rq*Nq];
  __shared__ __align__(16) float rcl[Rq*Nq];
  __shared__ __align__(16) float fwl[Rq*Nq];   // alpha: fw sums | links: fwacc
  __shared__ __align__(16) float bwl[Rq*Nq];
  __shared__ __align__(16) float xil[XIDq+9];
  __shared__ __align__(16) float wwl[Nq];
  __shared__ __align__(16) float precl[Nq];
  __shared__ __align__(16) float usage[Nq];
  __shared__ __align__(16) float uarr[Nq];
  __shared__ __align__(16) float cpl[Nq];
  __shared__ __align__(16) int   sidx[Nq];
  __shared__ __align__(16) float wcas[Nq];     // alpha: prl then wca
  __shared__ __align__(16) float inv[DINq];
  __shared__ __align__(16) float zl[Wq];
  __shared__ __align__(16) float hsl[Wq];
  __shared__ __align__(16) float acc4[4*Wq];
  __shared__ float s8[8];

  if (isA){
    // ================= ALPHA (fat) =================
    float4 m4[8][4];       // memv rows g2*64+w*8+rg, cols [c0,c0+16)
    float  nrm[8];
    #pragma unroll
    for (int g2=0;g2<8;g2++){
      const float4* src=(const float4*)(p.mem0 + ((size_t)b*Nq + g2*64 + w*8 + rg)*Mq + c0);
      float s=0.f;
      #pragma unroll
      for (int i=0;i<4;i++){ m4[g2][i]=src[i]; s+=dot4(m4[g2][i],m4[g2][i]); }
      nrm[g2]=sqrtf(red_cg(s));
    }
    for (int i=tid;i<Rq*Nq;i+=512) rwl[i]=0.f;
    usage[tid]=0.f; precl[tid]=0.f; wwl[tid]=0.f;
    if (tid<Wq) hsl[tid]=p.hs0[b*Wq+tid];
    __syncthreads();

    for (int t=0;t<=Tq;t++){
      // ---- combine rw(t-1): fw/bw from links, rca local (rcl) ----
      if (t>0){
        waitge(CNT_FW, 8u*(unsigned)t);
        #pragma unroll
        for (int k=0;k<4;k++){
          int idx=tid+k*512;
          float f=0.f;
          #pragma unroll
          for (int gg=0;gg<8;gg++) f+=pld(T+TF_FW+gg*2048+idx);
          fwl[idx]=f;
          bwl[idx]=pld(T+TF_BW+idx);
        }
        __syncthreads();
        #pragma unroll
        for (int r=0;r<Rq;r++){
          float v=rcl[r*Nq+tid];
          float mx=blk_max(v,s8);
          float e=expf(v-mx);
          float se=blk_sum(e,s8);
          rcl[r*Nq+tid]=e/se;
        }
        __syncthreads();
        #pragma unroll
        for (int k=0;k<4;k++){
          int idx=tid+k*512, r=idx>>9;
          float m0=xil[904+r*3],m1=xil[905+r*3],m2=xil[906+r*3];
          float mm=fmaxf(m0,fmaxf(m1,m2));
          float e0=expf(m0-mm),e1=expf(m1-mm),e2=expf(m2-mm);
          float es=e0+e1+e2;
          float rwv=(e0*bwl[idx]+e1*rcl[idx]+e2*fwl[idx])/es;
          rwl[idx]=rwv;
          pst(T+TF_RW+idx,rwv);
        }
      } else {
        #pragma unroll
        for (int k=0;k<4;k++){ int idx=tid+k*512; rwl[idx]=0.f; pst(T+TF_RW+idx,0.f); }
      }
      bump(FLAG_RW);   // links can start pulling rw
      // ---- reads(t-1) from register memv ----
      { float* prl=wcas;
        prl[tid]=0.f;
        __syncthreads();
        if (t>0){
          #pragma unroll
          for (int r=0;r<Rq;r++){
            float4 a0=make_float4(0.f,0.f,0.f,0.f),a1=a0,a2=a0,a3=a0;
            #pragma unroll
            for (int g2=0;g2<8;g2++){
              float rwn=rwl[r*Nq + g2*64 + w*8 + rg];
              a0.x+=rwn*m4[g2][0].x; a0.y+=rwn*m4[g2][0].y; a0.z+=rwn*m4[g2][0].z; a0.w+=rwn*m4[g2][0].w;
              a1.x+=rwn*m4[g2][1].x; a1.y+=rwn*m4[g2][1].y; a1.z+=rwn*m4[g2][1].z; a1.w+=rwn*m4[g2][1].w;
              a2.x+=rwn*m4[g2][2].x; a2.y+=rwn*m4[g2][2].y; a2.z+=rwn*m4[g2][2].z; a2.w+=rwn*m4[g2][2].w;
              a3.x+=rwn*m4[g2][3].x; a3.y+=rwn*m4[g2][3].y; a3.z+=rwn*m4[g2][3].z; a3.w+=rwn*m4[g2][3].w;
            }
            a0.x=red_rg(a0.x); a0.y=red_rg(a0.y); a0.z=red_rg(a0.z); a0.w=red_rg(a0.w);
            a1.x=red_rg(a1.x); a1.y=red_rg(a1.y); a1.z=red_rg(a1.z); a1.w=red_rg(a1.w);
            a2.x=red_rg(a2.x); a2.y=red_rg(a2.y); a2.z=red_rg(a2.z); a2.w=red_rg(a2.w);
            a3.x=red_rg(a3.x); a3.y=red_rg(a3.y); a3.z=red_rg(a3.z); a3.w=red_rg(a3.w);
            if (rg==0){
              atomicAdd(&prl[r*Wq+c0+ 0],a0.x); atomicAdd(&prl[r*Wq+c0+ 1],a0.y);
              atomicAdd(&prl[r*Wq+c0+ 2],a0.z); atomicAdd(&prl[r*Wq+c0+ 3],a0.w);
              atomicAdd(&prl[r*Wq+c0+ 4],a1.x); atomicAdd(&prl[r*Wq+c0+ 5],a1.y);
              atomicAdd(&prl[r*Wq+c0+ 6],a1.z); atomicAdd(&prl[r*Wq+c0+ 7],a1.w);
              atomicAdd(&prl[r*Wq+c0+ 8],a2.x); atomicAdd(&prl[r*Wq+c0+ 9],a2.y);
              atomicAdd(&prl[r*Wq+c0+10],a2.z); atomicAdd(&prl[r*Wq+c0+11],a2.w);
              atomicAdd(&prl[r*Wq+c0+12],a3.x); atomicAdd(&prl[r*Wq+c0+13],a3.y);
              atomicAdd(&prl[r*Wq+c0+14],a3.z); atomicAdd(&prl[r*Wq+c0+15],a3.w);
            }
          }
        }
        __syncthreads();
        inv[Wq+tid]=prl[tid];
        if (t>0) p.rdh[((size_t)b*Tq+(t-1))*Nq+tid]=prl[tid];
        __syncthreads();
      }
      if (t==Tq) break;
      float keep=1.f-(float)p.rst[b*Tq+t];
      if (tid<Wq){ inv[tid]=p.X[((size_t)b*Tq+t)*Wq+tid]; inv[Wq+Nq+tid]=keep*hsl[tid]; }
      __syncthreads();
      // ---- z ----
      { int j=tid>>2,q=tid&3;
        const float4* w4=(const float4*)(p.WbT+(size_t)j*DINq);
        const float4* i4=(const float4*)inv;
        float a=0.f;
        for (int c=q;c<192;c+=4) a+=dot4(w4[c],i4[c]);
        a+=__shfl_xor(a,1,4); a+=__shfl_xor(a,2,4);
        if (q==0){ a+=p.bb[j]; zl[j]=a*sigf(a); }
      }
      __syncthreads();
      // ---- hs ----
      { int which=tid>>7,j=tid&127;
        const float* Wg=(which==0)?p.Wff1T:(which==1)?p.Wff2T:(which==2)?p.WtaT:p.WtbT;
        const float4* w4=(const float4*)(Wg+(size_t)j*Wq);
        const float4* z4=(const float4*)zl;
        float a=0.f;
        #pragma unroll 8
        for (int c=0;c<32;c++) a+=dot4(w4[c],z4[c]);
        acc4[which*Wq+j]=a;
      }
      __syncthreads();
      if (tid<Wq){
        float a1=acc4[tid]+p.bff1[tid],a2=acc4[Wq+tid]+p.bff2[tid];
        float aa=acc4[2*Wq+tid]+p.bta[tid],ab=acc4[3*Wq+tid]+p.btb[tid];
        float ti=sigf(aa*(float)t+ab);
        float h=a1*(1.f-ti)+ti*a2;
        hsl[tid]=h;
        p.out[BTWq+((size_t)b*Tq+t)*Wq+tid]=h;
      }
      __syncthreads();
      // ---- xi full ----
      { const float4* h4=(const float4*)hsl;
        { const float4* w4=(const float4*)(p.WxiT+(size_t)tid*Wq);
          float a=p.bxi[tid];
          #pragma unroll 8
          for (int c=0;c<32;c++) a+=dot4(w4[c],h4[c]);
          xil[tid]=a;
        }
        int f2=tid+512;
        if (f2<XIDq){
          const float4* w4=(const float4*)(p.WxiT+(size_t)f2*Wq);
          float a=p.bxi[f2];
          #pragma unroll 8
          for (int c=0;c<32;c++) a+=dot4(w4[c],h4[c]);
          xil[f2]=a;
        }
      }
      __syncthreads();
      // ---- wca from register memv ----
      { float kk=(tid<Wq)? xil[512+tid]*xil[512+tid]:0.f;
        float kn=sqrtf(blk_sum(kk,s8));
        const float4* k4=(const float4*)(xil+512);
        float wstr=oneplusf(xil[916]);
        #pragma unroll
        for (int g2=0;g2<8;g2++){
          float d=dot4(k4[cg*4+0],m4[g2][0])+dot4(k4[cg*4+1],m4[g2][1])
                 +dot4(k4[cg*4+2],m4[g2][2])+dot4(k4[cg*4+3],m4[g2][3]);
          d=red_cg(d);
          float sim=(keep*d)/(kn*(keep*nrm[g2])+1e-6f);
          if (cg==0) wcas[g2*64+w*8+rg]=wstr*sim;
        }
        __syncthreads();
        float v=wcas[tid];
        float mx=blk_max(v,s8);
        float e=expf(v-mx);
        float se=blk_sum(e,s8);
        wcas[tid]=e/se;
      }
      __syncthreads();
      // ---- usage / rank-sort / cumprod / alloc / ww / prec ----
      { int n=tid;
        float ret=1.f;
        #pragma unroll
        for (int r=0;r<Rq;r++) ret*=1.f-sigf(xil[896+r])*rwl[r*Nq+n];
        float uo=usage[n],pw=wwl[n];
        float u=(uo+pw-uo*pw)*ret;
        usage[n]=u; uarr[n]=u;
        __syncthreads();
        int rank=0;
        const float4* u4=(const float4*)uarr;
        #pragma unroll 8
        for (int jj=0;jj<128;jj++){
          float4 vv=u4[jj]; int j0=jj*4;
          rank+=(vv.x<u)||(vv.x==u&&(j0+0)<n);
          rank+=(vv.y<u)||(vv.y==u&&(j0+1)<n);
          rank+=(vv.z<u)||(vv.z==u&&(j0+2)<n);
          rank+=(vv.w<u)||(vv.w==u&&(j0+3)<n);
        }
        sidx[rank]=n;
        __syncthreads();
        int si=sidx[n];
        float sv=uarr[si];
        float x=sv;
        #pragma unroll
        for (int dd=1;dd<64;dd<<=1){ float pr=__shfl_up(x,dd,64); if (l>=dd) x*=pr; }
        if (l==63) s8[w]=x;
        __syncthreads();
        float woff=1.f;
        #pragma unroll
        for (int q=0;q<8;q++) if (q<w) woff*=s8[q];
        x*=woff;
        cpl[n]=x;
        __syncthreads();
        float alloc=(1.f-u)*cpl[si];      // reference's cp[si[k]] indexing
        float ag=sigf(xil[917]),wg=sigf(xil[918]);
        float wwv=wg*(ag*alloc+(1.f-ag)*wcas[n]);
        wwl[n]=wwv;
        pst(T+TF_WW+n,wwv);
        float wsum=blk_sum(wwv,s8);
        float pn=(1.f-wsum)*precl[n]+wwv;
        precl[n]=pn;
        pst(T+TF_PREC+(t&1)*Nq+n,pn);
      }
      bump(FLAG_WW);
      // ---- mem update (registers) + new norms + rca raw scores ----
      { float4 e4v[4], wv4v[4];
        #pragma unroll
        for (int i=0;i<4;i++){
          e4v[i].x=sigf(xil[768+c0+i*4+0]); e4v[i].y=sigf(xil[768+c0+i*4+1]);
          e4v[i].z=sigf(xil[768+c0+i*4+2]); e4v[i].w=sigf(xil[768+c0+i*4+3]);
          wv4v[i].x=xil[640+c0+i*4+0]; wv4v[i].y=xil[640+c0+i*4+1];
          wv4v[i].z=xil[640+c0+i*4+2]; wv4v[i].w=xil[640+c0+i*4+3];
        }
        #pragma unroll
        for (int g2=0;g2<8;g2++){
          float wwn=wwl[g2*64+w*8+rg];
          float s=0.f;
          #pragma unroll
          for (int i=0;i<4;i++){
            m4[g2][i].x=m4[g2][i].x*keep*(1.f-wwn*e4v[i].x)+wwn*wv4v[i].x;
            m4[g2][i].y=m4[g2][i].y*keep*(1.f-wwn*e4v[i].y)+wwn*wv4v[i].y;
            m4[g2][i].z=m4[g2][i].z*keep*(1.f-wwn*e4v[i].z)+wwn*wv4v[i].z;
            m4[g2][i].w=m4[g2][i].w*keep*(1.f-wwn*e4v[i].w)+wwn*wv4v[i].w;
            s+=dot4(m4[g2][i],m4[g2][i]);
          }
          nrm[g2]=sqrtf(red_cg(s));
        }
        float kn4[Rq], rstr[Rq];
        #pragma unroll
        for (int r=0;r<Rq;r++){
          float kk=(tid<Wq)? xil[r*Wq+tid]*xil[r*Wq+tid]:0.f;
          kn4[r]=sqrtf(blk_sum(kk,s8));
          rstr[r]=oneplusf(xil[900+r]);
        }
        #pragma unroll
        for (int r=0;r<Rq;r++){
          const float4* kr=(const float4*)(xil+r*Wq);
          #pragma unroll
          for (int g2=0;g2<8;g2++){
            float d=dot4(kr[cg*4+0],m4[g2][0])+dot4(kr[cg*4+1],m4[g2][1])
                   +dot4(kr[cg*4+2],m4[g2][2])+dot4(kr[cg*4+3],m4[g2][3]);
            d=red_cg(d);
            float v=rstr[r]*(d/(kn4[r]*nrm[g2]+1e-6f));
            if (cg==0) rcl[r*Nq+g2*64+w*8+rg]=v;
          }
        }
      }
      __syncthreads();
    } // t loop (alpha)
  } else {
    // ================= LINK (skinny) =================
    float Lreg[8][8];
    #pragma unroll
    for (int rr=0;rr<8;rr++)
      #pragma unroll
      for (int q=0;q<8;q++) Lreg[rr][q]=0.f;

    for (int t=0;t<Tq;t++){
      waitge(FLAG_RW, (unsigned)(t+1));
      for (int i=tid;i<Rq*Nq;i+=512) rwl[i]=pld(T+TF_RW+i);
      precl[tid]=pld(T+TF_PREC+((t&1)^1)*Nq+tid);
      waitge(FLAG_WW,(unsigned)(t+1));
      wwl[tid]=pld(T+TF_WW+tid);
      __syncthreads();
      // ---- link update (registers) + fw/bw ----
      { float* fwacc=fwl;
        int c0p=l*8;
        float ww8[8],pc8[8],pr8[Rq][8];
        *(float4*)&ww8[0]=*(const float4*)&wwl[c0p];   *(float4*)&ww8[4]=*(const float4*)&wwl[c0p+4];
        *(float4*)&pc8[0]=*(const float4*)&precl[c0p]; *(float4*)&pc8[4]=*(const float4*)&precl[c0p+4];
        #pragma unroll
        for (int r=0;r<Rq;r++){
          *(float4*)&pr8[r][0]=*(const float4*)&rwl[r*Nq+c0p];
          *(float4*)&pr8[r][4]=*(const float4*)&rwl[r*Nq+c0p+4];
        }
        float fa[Rq][8];
        #pragma unroll
        for (int r=0;r<Rq;r++)
          #pragma unroll
          for (int q=0;q<8;q++) fa[r][q]=0.f;
        #pragma unroll
        for (int rr=0;rr<8;rr++){
          int n2=g*64+w*8+rr;
          float wwn=wwl[n2];
          float prn[Rq];
          #pragma unroll
          for (int r=0;r<Rq;r++) prn[r]=rwl[r*Nq+n2];
          float bwp[Rq]={0.f,0.f,0.f,0.f};
          #pragma unroll
          for (int q=0;q<8;q++){
            float nv=(1.f-wwn-ww8[q])*Lreg[rr][q]+wwn*pc8[q];
            if (c0p+q==n2) nv=0.f;
            Lreg[rr][q]=nv;
            #pragma unroll
            for (int r=0;r<Rq;r++){ fa[r][q]+=prn[r]*nv; bwp[r]+=pr8[r][q]*nv; }
          }
          #pragma unroll
          for (int mm=1;mm<64;mm<<=1)
            #pragma unroll
            for (int r=0;r<Rq;r++) bwp[r]+=__shfl_xor(bwp[r],mm,64);
          if (l==0){
            #pragma unroll
            for (int r=0;r<Rq;r++) pst(T+TF_BW+r*Nq+n2, bwp[r]);
          }
        }
        // wave-serialized fw accumulation
        for (int k=0;k<8;k++){
          if (w==k){
            #pragma unroll
            for (int r=0;r<Rq;r++)
              #pragma unroll
              for (int q=0;q<8;q++){
                if (k==0) fwacc[r*Nq+c0p+q]=fa[r][q];
                else      fwacc[r*Nq+c0p+q]+=fa[r][q];
              }
          }
          __syncthreads();
        }
        for (int i=tid;i<Rq*Nq;i+=512) pst(T+TF_FW+g*2048+i,fwacc[i]);
      }
      bump(CNT_FW);
    }
  }
}

// ---------- k_y: all outputs y[b][t][j] ----------
__global__ __launch_bounds__(512) void k_y(P p){
  int j=blockIdx.x, tid=threadIdx.x;
  __shared__ __align__(16) float wv[Wq];
  __shared__ __align__(16) float wr[Rq*Wq];
  if (tid<Wq) wv[tid]=p.WvT[(size_t)j*Wq+tid];
  wr[tid]=p.WrT[(size_t)j*(Rq*Wq)+tid];
  __syncthreads();
  int b=tid>>5, t=tid&31;
  const float4* h4=(const float4*)(p.out+BTWq+((size_t)b*Tq+t)*Wq);
  const float4* r4=(const float4*)(p.rdh+((size_t)b*Tq+t)*Nq);
  const float4* wv4=(const float4*)wv;
  const float4* wr4=(const float4*)wr;
  float a=0.f;
  #pragma unroll 8
  for (int c=0;c<32;c++) a+=dot4(wv4[c],h4[c]);
  #pragma unroll 8
  for (int c=0;c<128;c++) a+=dot4(wr4[c],r4[c]);
  p.out[((size_t)b*Tq+t)*Wq+j]=a+p.bv[j]+p.br[j];
}

extern "C" void kernel_launch(void* const* d_in, const int* in_sizes, int n_in,
                              void* d_out, int out_size, void* d_ws, size_t ws_size,
                              hipStream_t stream){
  (void)in_sizes; (void)n_in; (void)out_size; (void)ws_size;
  P p;
  p.X    = (const float*)d_in[0];
  p.hs0  = (const float*)d_in[1];
  p.mem0 = (const float*)d_in[2];
  p.rst  = (const int*)d_in[3];
  p.Wb   = (const float*)d_in[4];  p.bb   = (const float*)d_in[5];
  p.Wff1 = (const float*)d_in[6];  p.bff1 = (const float*)d_in[7];
  p.Wff2 = (const float*)d_in[8];  p.bff2 = (const float*)d_in[9];
  p.Wta  = (const float*)d_in[10]; p.bta  = (const float*)d_in[11];
  p.Wtb  = (const float*)d_in[12]; p.btb  = (const float*)d_in[13];
  p.Wv   = (const float*)d_in[14]; p.bv   = (const float*)d_in[15];
  p.Wr   = (const float*)d_in[16]; p.br   = (const float*)d_in[17];
  p.Wxi  = (const float*)d_in[18]; p.bxi  = (const float*)d_in[19];
  p.out  = (float*)d_out;
  float* ws = (float*)d_ws;
  size_t o = 0;
  p.rdh   = ws + o; o += (size_t)Bq*Tq*Nq;    //   262,144
  p.teams = ws + o; o += (size_t)16*TSTRIDE;  //   356,352
  p.WbT   = ws + o; o += (size_t)DINq*Wq;
  p.Wff1T = ws + o; o += (size_t)Wq*Wq;
  p.Wff2T = ws + o; o += (size_t)Wq*Wq;
  p.WtaT  = ws + o; o += (size_t)Wq*Wq;
  p.WtbT  = ws + o; o += (size_t)Wq*Wq;
  p.WvT   = ws + o; o += (size_t)Wq*Wq;
  p.WrT   = ws + o; o += (size_t)Rq*Wq*Wq;
  p.WxiT  = ws + o; o += (size_t)XIDq*Wq;

  hipLaunchKernelGGL(k_init, dim3(38),  dim3(256), 0, stream, p);
  hipLaunchKernelGGL(k_run,  dim3(144), dim3(512), 0, stream, p);
  hipLaunchKernelGGL(k_y,    dim3(128), dim3(512), 0, stream, p);
}